// Round 1
// baseline (339.548 us; speedup 1.0000x reference)
//
#include <hip/hip_runtime.h>

#define B_ROWS  2048
#define T_DIM   8
#define IN_DIM  1024
#define OUT_DIM 4096
#define NE      12

#define M_TILE 128
#define N_TILE 128
#define K_STEP 32
#define LDS_PAD 48   // elements per row; 96B stride = multiple of 16B

typedef __attribute__((ext_vector_type(8))) short short8;
typedef __attribute__((ext_vector_type(4))) float f32x4;

__device__ __forceinline__ unsigned short f2bf(float f) {
  union { float f; unsigned int u; } v; v.f = f;
  unsigned int u = v.u;
  unsigned int r = (u + 0x7FFFu + ((u >> 16) & 1u)) >> 16;  // RNE
  return (unsigned short)r;
}

// ---------------- kernel A: gate logits -> top1 -> per-expert row buckets ----
__global__ __launch_bounds__(256) void gate_kernel(
    const float* __restrict__ t, const float* __restrict__ Wg,
    const float* __restrict__ bg, int* __restrict__ counts,
    int* __restrict__ rowlist)
{
  const int b   = blockIdx.x;
  const int tid = threadIdx.x;
  const float* tb = t + (size_t)b * T_DIM * OUT_DIM;

  float part[NE];
  #pragma unroll
  for (int e = 0; e < NE; ++e) part[e] = 0.f;

  // each thread owns 16 columns (4 float4 chunks) of t_mean
  #pragma unroll
  for (int it = 0; it < 4; ++it) {
    const int c = (tid + it * 256) * 4;
    float4 s = make_float4(0.f, 0.f, 0.f, 0.f);
    #pragma unroll
    for (int tt = 0; tt < T_DIM; ++tt) {
      const float4 v = *(const float4*)(tb + (size_t)tt * OUT_DIM + c);
      s.x += v.x; s.y += v.y; s.z += v.z; s.w += v.w;
    }
    const float m[4] = { s.x * 0.125f, s.y * 0.125f, s.z * 0.125f, s.w * 0.125f };
    #pragma unroll
    for (int j = 0; j < 4; ++j) {
      const float* wg = Wg + (size_t)(c + j) * NE;
      #pragma unroll
      for (int e = 0; e < NE; ++e) part[e] += m[j] * wg[e];
    }
  }

  // block reduction in double (argmax near-tie safety vs np reference)
  __shared__ double red[256][NE];
  #pragma unroll
  for (int e = 0; e < NE; ++e) red[tid][e] = (double)part[e];
  __syncthreads();
  for (int s = 128; s > 0; s >>= 1) {
    if (tid < s) {
      #pragma unroll
      for (int e = 0; e < NE; ++e) red[tid][e] += red[tid + s][e];
    }
    __syncthreads();
  }
  if (tid == 0) {
    double best = red[0][0] + (double)bg[0];
    int bi = 0;
    #pragma unroll
    for (int e = 1; e < NE; ++e) {
      const double v = red[0][e] + (double)bg[e];
      if (v > best) { best = v; bi = e; }   // strict > : first max wins (argmax semantics)
    }
    const int pos = atomicAdd(&counts[bi], 1);
    rowlist[bi * B_ROWS + pos] = b;
  }
}

// ---------------- kernel B: grouped bf16-MFMA GEMM over selected experts ----
__global__ __launch_bounds__(256) void expert_gemm(
    const float* __restrict__ x, const float* __restrict__ W,
    const float* __restrict__ bias, const int* __restrict__ counts,
    const int* __restrict__ rowlist, float* __restrict__ out)
{
  const int e    = blockIdx.z;
  const int cnt  = counts[e];
  const int row0 = blockIdx.y * M_TILE;
  if (row0 >= cnt) return;                 // over-provisioned grid: early exit
  const int c0   = blockIdx.x * N_TILE;
  const int* rl  = rowlist + e * B_ROWS;

  __shared__ unsigned short xs[M_TILE][LDS_PAD];  // x tile  [row][k]  (bf16)
  __shared__ unsigned short wt[N_TILE][LDS_PAD];  // W tile  [col][k]  (bf16, transposed)

  const int tid = threadIdx.x;

  // x staging: thread -> rows (tid>>3)+32i, k-quad (tid&7)*4
  const int xr = tid >> 3;
  const int kq = (tid & 7) * 4;
  int srcrow[4];
  #pragma unroll
  for (int i = 0; i < 4; ++i) {
    const int g = row0 + xr + 32 * i;
    srcrow[i] = (g < cnt) ? rl[g] : -1;
  }

  // W staging: thread -> k rows (tid>>5)+8i, col-quad (tid&31)*4
  const int kw = tid >> 5;
  const int cw = (tid & 31) * 4;
  const float* Wb = W + ((size_t)e * IN_DIM) * OUT_DIM + c0;

  const int lane = tid & 63;
  const int wave = tid >> 6;
  const int wm = (wave >> 1) * 64;   // wave's row offset in tile
  const int wn = (wave & 1) * 64;    // wave's col offset in tile
  const int lr = lane & 15;
  const int lk = (lane >> 4) * 8;

  f32x4 acc[4][4];
  #pragma unroll
  for (int m = 0; m < 4; ++m)
    #pragma unroll
    for (int n = 0; n < 4; ++n)
      #pragma unroll
      for (int q = 0; q < 4; ++q) acc[m][n][q] = 0.f;

  for (int k0 = 0; k0 < IN_DIM; k0 += K_STEP) {
    // stage x (M_TILE x K_STEP), gathered rows, f32 -> bf16
    #pragma unroll
    for (int i = 0; i < 4; ++i) {
      float4 v = make_float4(0.f, 0.f, 0.f, 0.f);
      if (srcrow[i] >= 0)
        v = *(const float4*)(x + (size_t)srcrow[i] * IN_DIM + k0 + kq);
      ushort4 u;
      u.x = f2bf(v.x); u.y = f2bf(v.y); u.z = f2bf(v.z); u.w = f2bf(v.w);
      *(ushort4*)&xs[xr + 32 * i][kq] = u;
    }
    // stage W (K_STEP x N_TILE) transposed into [col][k], f32 -> bf16
    #pragma unroll
    for (int i = 0; i < 4; ++i) {
      const int k = kw + 8 * i;
      const float4 v = *(const float4*)(Wb + (size_t)(k0 + k) * OUT_DIM + cw);
      wt[cw + 0][k] = f2bf(v.x);
      wt[cw + 1][k] = f2bf(v.y);
      wt[cw + 2][k] = f2bf(v.z);
      wt[cw + 3][k] = f2bf(v.w);
    }
    __syncthreads();

    short8 af[4], bf[4];
    #pragma unroll
    for (int m = 0; m < 4; ++m)
      af[m] = *(const short8*)&xs[wm + m * 16 + lr][lk];
    #pragma unroll
    for (int n = 0; n < 4; ++n)
      bf[n] = *(const short8*)&wt[wn + n * 16 + lr][lk];
    #pragma unroll
    for (int m = 0; m < 4; ++m)
      #pragma unroll
      for (int n = 0; n < 4; ++n)
        acc[m][n] = __builtin_amdgcn_mfma_f32_16x16x32_bf16(af[m], bf[n], acc[m][n], 0, 0, 0);
    __syncthreads();
  }

  // epilogue: D layout col = lane&15, row = (lane>>4)*4 + r ; scatter to gathered rows
  const int lq = (lane >> 4) * 4;
  #pragma unroll
  for (int m = 0; m < 4; ++m) {
    #pragma unroll
    for (int r = 0; r < 4; ++r) {
      const int gidx = row0 + wm + m * 16 + lq + r;
      if (gidx >= cnt) continue;
      const int grow = rl[gidx];
      float* orow = out + (size_t)grow * OUT_DIM;
      #pragma unroll
      for (int n = 0; n < 4; ++n) {
        const int col = c0 + wn + n * 16 + lr;
        orow[col] = acc[m][n][r] + bias[e * OUT_DIM + col];
      }
    }
  }
}

extern "C" void kernel_launch(void* const* d_in, const int* in_sizes, int n_in,
                              void* d_out, int out_size, void* d_ws, size_t ws_size,
                              hipStream_t stream) {
  (void)in_sizes; (void)n_in; (void)out_size; (void)ws_size;
  const float* x  = (const float*)d_in[0];
  const float* t  = (const float*)d_in[1];
  const float* W  = (const float*)d_in[2];
  const float* bb = (const float*)d_in[3];
  const float* Wg = (const float*)d_in[4];
  const float* bg = (const float*)d_in[5];
  float* out = (float*)d_out;

  int* counts  = (int*)d_ws;            // 16 ints
  int* rowlist = (int*)d_ws + 16;       // 12 * 2048 ints

  hipMemsetAsync(counts, 0, 16 * sizeof(int), stream);
  gate_kernel<<<B_ROWS, 256, 0, stream>>>(t, Wg, bg, counts, rowlist);

  dim3 grid(OUT_DIM / N_TILE, (B_ROWS + M_TILE - 1) / M_TILE, NE);
  expert_gemm<<<grid, 256, 0, stream>>>(x, W, bb, counts, rowlist, out);
}

// Round 2
// 203.140 us; speedup vs baseline: 1.6715x; 1.6715x over previous
//
#include <hip/hip_runtime.h>

#define B_ROWS  2048
#define T_DIM   8
#define IN_DIM  1024
#define OUT_DIM 4096
#define NE      12

#define M_TILE 128
#define N_TILE 128
#define K_STEP 32

typedef __attribute__((ext_vector_type(8))) short short8;
typedef __attribute__((ext_vector_type(4))) float f32x4;

// pack two floats -> two RNE bf16 in one u32 (lo = x, hi = y)
__device__ __forceinline__ unsigned int packbf2(float x, float y) {
  union { float f; unsigned u; } ax, ay; ax.f = x; ay.f = y;
  unsigned lo = (ax.u + 0x7FFFu + ((ax.u >> 16) & 1u)) >> 16;
  unsigned hi = (ay.u + 0x7FFFu + ((ay.u >> 16) & 1u)) & 0xFFFF0000u;
  return hi | lo;
}

union S8U {
  short8 s;
  unsigned u[4];
};

// ---------------- kernel A: gate logits -> top1 -> per-expert row buckets ----
// (numerics identical to round-1 passing version: do not perturb argmax ties)
__global__ __launch_bounds__(256) void gate_kernel(
    const float* __restrict__ t, const float* __restrict__ Wg,
    const float* __restrict__ bg, int* __restrict__ counts,
    int* __restrict__ rowlist)
{
  const int b   = blockIdx.x;
  const int tid = threadIdx.x;
  const float* tb = t + (size_t)b * T_DIM * OUT_DIM;

  float part[NE];
  #pragma unroll
  for (int e = 0; e < NE; ++e) part[e] = 0.f;

  #pragma unroll
  for (int it = 0; it < 4; ++it) {
    const int c = (tid + it * 256) * 4;
    float4 s = make_float4(0.f, 0.f, 0.f, 0.f);
    #pragma unroll
    for (int tt = 0; tt < T_DIM; ++tt) {
      const float4 v = *(const float4*)(tb + (size_t)tt * OUT_DIM + c);
      s.x += v.x; s.y += v.y; s.z += v.z; s.w += v.w;
    }
    const float m[4] = { s.x * 0.125f, s.y * 0.125f, s.z * 0.125f, s.w * 0.125f };
    #pragma unroll
    for (int j = 0; j < 4; ++j) {
      const float* wg = Wg + (size_t)(c + j) * NE;
      #pragma unroll
      for (int e = 0; e < NE; ++e) part[e] += m[j] * wg[e];
    }
  }

  __shared__ double red[256][NE];
  #pragma unroll
  for (int e = 0; e < NE; ++e) red[tid][e] = (double)part[e];
  __syncthreads();
  for (int s = 128; s > 0; s >>= 1) {
    if (tid < s) {
      #pragma unroll
      for (int e = 0; e < NE; ++e) red[tid][e] += red[tid + s][e];
    }
    __syncthreads();
  }
  if (tid == 0) {
    double best = red[0][0] + (double)bg[0];
    int bi = 0;
    #pragma unroll
    for (int e = 1; e < NE; ++e) {
      const double v = red[0][e] + (double)bg[e];
      if (v > best) { best = v; bi = e; }
    }
    const int pos = atomicAdd(&counts[bi], 1);
    rowlist[bi * B_ROWS + pos] = b;
  }
}

// ---------------- kernel B: grouped bf16-MFMA GEMM, fragment-order LDS ------
// LDS slot s (s in [0,512)): mb = s>>6, g = (s>>4)&3, lr = s&15.
//   xa[s] = bf16 x[rl[row0 + 16*mb + lr]][k0 + 8*g + j]        j = 0..7
//   wb[s] = bf16 W[k0 + 8*g + j][c0 + 16*nb + lc]  (nb=mb, lc=lr)
// MFMA lane l consumes slot (fragblock*64 + l): all LDS reads AND writes are
// wave-contiguous ds_*_b128 (1 KiB per wave op) -> zero bank conflicts.
__global__ __launch_bounds__(256) void expert_gemm(
    const float* __restrict__ x, const float* __restrict__ W,
    const float* __restrict__ bias, const int* __restrict__ counts,
    const int* __restrict__ rowlist, float* __restrict__ out)
{
  const int e    = blockIdx.z;
  const int cnt  = counts[e];
  const int row0 = blockIdx.y * M_TILE;
  if (row0 >= cnt) return;
  const int c0   = blockIdx.x * N_TILE;
  const int* rl  = rowlist + e * B_ROWS;

  __shared__ short8 xa[512];   // 8 KiB
  __shared__ short8 wb[512];   // 8 KiB

  const int tid  = threadIdx.x;
  const int lane = tid & 63;
  const int wave = tid >> 6;

  // ---- staging geometry: thread t owns slots {t, t+256} on both sides ----
  const int sg  = (tid >> 4) & 3;   // g (k-subgroup) for both slots
  const int slr = tid & 15;         // lr / lc for both slots
  const int smb = tid >> 6;         // mb for slot t; slot t+256 has mb+4

  // A: gathered source rows (clamped; pad rows compute garbage, never stored)
  int arow0, arow1;
  {
    const int g0 = row0 + smb * 16 + slr;
    const int g1 = row0 + (smb + 4) * 16 + slr;
    arow0 = rl[g0 < cnt ? g0 : cnt - 1];
    arow1 = rl[g1 < cnt ? g1 : cnt - 1];
  }
  const float* xp0 = x + (size_t)arow0 * IN_DIM + sg * 8;
  const float* xp1 = x + (size_t)arow1 * IN_DIM + sg * 8;

  // B: column bases (slot t: col c0+16*smb+slr ; slot t+256: +64 cols)
  const float* wp = W + (size_t)e * IN_DIM * OUT_DIM
                      + (size_t)(sg * 8) * OUT_DIM + c0 + smb * 16 + slr;

  // ---- MFMA geometry ----
  const int wm = (wave >> 1) * 64;      // wave row offset in tile
  const int wn = (wave & 1) * 64;       // wave col offset in tile
  const int abase = (wave >> 1) * 256;  // slot base for A fragments
  const int bbase = (wave & 1) * 256;   // slot base for B fragments

  f32x4 acc[4][4];
  #pragma unroll
  for (int m = 0; m < 4; ++m)
    #pragma unroll
    for (int n = 0; n < 4; ++n)
      #pragma unroll
      for (int q = 0; q < 4; ++q) acc[m][n][q] = 0.f;

  for (int k0 = 0; k0 < IN_DIM; k0 += K_STEP) {
    // ---- load + convert in registers ----
    S8U av0, av1, bv0, bv1;
    {
      const float4 u0 = *(const float4*)(xp0 + k0);
      const float4 u1 = *(const float4*)(xp0 + k0 + 4);
      av0.u[0] = packbf2(u0.x, u0.y); av0.u[1] = packbf2(u0.z, u0.w);
      av0.u[2] = packbf2(u1.x, u1.y); av0.u[3] = packbf2(u1.z, u1.w);
      const float4 v0 = *(const float4*)(xp1 + k0);
      const float4 v1 = *(const float4*)(xp1 + k0 + 4);
      av1.u[0] = packbf2(v0.x, v0.y); av1.u[1] = packbf2(v0.z, v0.w);
      av1.u[2] = packbf2(v1.x, v1.y); av1.u[3] = packbf2(v1.z, v1.w);
    }
    {
      const float* p = wp + (size_t)k0 * OUT_DIM;
      float f0[8], f1[8];
      #pragma unroll
      for (int j = 0; j < 8; ++j) {
        f0[j] = p[(size_t)j * OUT_DIM];
        f1[j] = p[(size_t)j * OUT_DIM + 64];
      }
      #pragma unroll
      for (int q = 0; q < 4; ++q) {
        bv0.u[q] = packbf2(f0[2 * q], f0[2 * q + 1]);
        bv1.u[q] = packbf2(f1[2 * q], f1[2 * q + 1]);
      }
    }

    __syncthreads();                 // previous iteration's reads complete
    xa[tid]       = av0.s;
    xa[tid + 256] = av1.s;
    wb[tid]       = bv0.s;
    wb[tid + 256] = bv1.s;
    __syncthreads();                 // tiles visible

    short8 af[4], bf[4];
    #pragma unroll
    for (int m = 0; m < 4; ++m) af[m] = xa[abase + m * 64 + lane];
    #pragma unroll
    for (int n = 0; n < 4; ++n) bf[n] = wb[bbase + n * 64 + lane];
    #pragma unroll
    for (int m = 0; m < 4; ++m)
      #pragma unroll
      for (int n = 0; n < 4; ++n)
        acc[m][n] = __builtin_amdgcn_mfma_f32_16x16x32_bf16(af[m], bf[n], acc[m][n], 0, 0, 0);
  }

  // ---- epilogue: C/D layout col = lane&15, row = (lane>>4)*4 + r ----
  const int lr = lane & 15;
  const int lq = (lane >> 4) * 4;
  float bcol[4];
  #pragma unroll
  for (int n = 0; n < 4; ++n)
    bcol[n] = bias[e * OUT_DIM + c0 + wn + n * 16 + lr];

  #pragma unroll
  for (int m = 0; m < 4; ++m) {
    #pragma unroll
    for (int r = 0; r < 4; ++r) {
      const int gidx = row0 + wm + m * 16 + lq + r;
      if (gidx >= cnt) continue;
      const int grow = rl[gidx];
      float* orow = out + (size_t)grow * OUT_DIM;
      #pragma unroll
      for (int n = 0; n < 4; ++n) {
        const int col = c0 + wn + n * 16 + lr;
        orow[col] = acc[m][n][r] + bcol[n];
      }
    }
  }
}

extern "C" void kernel_launch(void* const* d_in, const int* in_sizes, int n_in,
                              void* d_out, int out_size, void* d_ws, size_t ws_size,
                              hipStream_t stream) {
  (void)in_sizes; (void)n_in; (void)out_size; (void)ws_size;
  const float* x  = (const float*)d_in[0];
  const float* t  = (const float*)d_in[1];
  const float* W  = (const float*)d_in[2];
  const float* bb = (const float*)d_in[3];
  const float* Wg = (const float*)d_in[4];
  const float* bg = (const float*)d_in[5];
  float* out = (float*)d_out;

  int* counts  = (int*)d_ws;            // 16 ints
  int* rowlist = (int*)d_ws + 16;       // 12 * 2048 ints

  hipMemsetAsync(counts, 0, 16 * sizeof(int), stream);
  gate_kernel<<<B_ROWS, 256, 0, stream>>>(t, Wg, bg, counts, rowlist);

  dim3 grid(OUT_DIM / N_TILE, (B_ROWS + M_TILE - 1) / M_TILE, NE);
  expert_gemm<<<grid, 256, 0, stream>>>(x, W, bb, counts, rowlist, out);
}